// Round 9
// baseline (312.939 us; speedup 1.0000x reference)
//
#include <hip/hip_runtime.h>
#include <stdint.h>

#define B_ 4
#define T_ 2048
#define C_ 768
#define H_ 12
#define D_ 64
#define BT_ (B_*T_)
#define C3_ (3*C_)
#define FMIN_ (-3.402823466e38f)
// 0.125 * log2(e): Q prescale so QK^T scores are in log2 units
#define QSCALE_ (0.18033688f)

typedef __attribute__((ext_vector_type(8))) short short8;
typedef __attribute__((ext_vector_type(4))) short s16x4;
typedef __attribute__((ext_vector_type(4))) float f32x4;

// async global->LDS DMA, 16B per lane; LDS dest = wave-uniform base + lane*16
#define GLDS16(g, l) __builtin_amdgcn_global_load_lds( \
    (const __attribute__((address_space(1))) void*)(g), \
    (__attribute__((address_space(3))) void*)(l), 16, 0, 0)

__device__ __forceinline__ float bf2f(unsigned short u) {
    union { unsigned int i; float f; } v; v.i = ((unsigned int)u) << 16; return v.f;
}
__device__ __forceinline__ unsigned short f2bf(float f) {
    union { float ff; unsigned int i; } v; v.ff = f;
    unsigned int r = v.i + 0x7fffu + ((v.i >> 16) & 1u);
    return (unsigned short)(r >> 16);
}
// packed f32x2 -> bf16x2 (RNE), single HW instr
__device__ __forceinline__ unsigned int cvtpk(float lo, float hi) {
    unsigned int r;
    asm("v_cvt_pk_bf16_f32 %0, %1, %2" : "=v"(r) : "v"(lo), "v"(hi));
    return r;
}
__device__ __forceinline__ float ldf(const void* p, size_t i, int isbf) {
    return isbf ? bf2f(((const unsigned short*)p)[i]) : ((const float*)p)[i];
}

// ---------------- wave-level self-detection (no cross-kernel flags) ----------------
// bf16 vs f32: even 16-bit words of bf16 data have exponent clustered ~118..132;
// f32 low-mantissa halves are ~uniform (P(hit)~0.16). 64 samples, threshold 32:
// misclassification probability ~1e-8.
__device__ __forceinline__ int detect_bf16(const void* p) {
    unsigned short u = ((const unsigned short*)p)[2 * (threadIdx.x & 63)];
    int e = (u >> 7) & 0xff;
    unsigned long long m = __ballot(e >= 100 && e <= 140);
    return __popcll(m) >= 32;
}
// mask mode: 1=int32 (all dwords 0/1), 2=f32 (all 0.0/1.0), 0=uint8/bool
__device__ __forceinline__ int detect_mask(const void* p) {
    unsigned int d = ((const unsigned int*)p)[threadIdx.x & 63];
    unsigned long long bi = __ballot(d <= 1u);
    unsigned long long bf = __ballot(d == 0u || d == 0x3f800000u);
    if (__popcll(bi) == 64) return 1;
    if (__popcll(bf) == 64) return 2;
    return 0;
}

// ---------------- canonicalize x -> bf16 ----------------
__global__ void k_canon_x(const void* x, unsigned short* xb) {
    const int n8 = BT_ * C_ / 8;
    int i = blockIdx.x * blockDim.x + threadIdx.x;
    if (i >= n8) return;
    if (detect_bf16(x)) {
        ((int4*)xb)[i] = ((const int4*)x)[i];
    } else {
        const float4* xf = (const float4*)x;
        float4 a = xf[2*i], b = xf[2*i+1];
        short8 o;
        o[0]=(short)f2bf(a.x); o[1]=(short)f2bf(a.y); o[2]=(short)f2bf(a.z); o[3]=(short)f2bf(a.w);
        o[4]=(short)f2bf(b.x); o[5]=(short)f2bf(b.y); o[6]=(short)f2bf(b.z); o[7]=(short)f2bf(b.w);
        *(short8*)&xb[8*i] = o;
    }
}

// ---------------- merged prep: both weight transposes + biases + mask ----------------
// range-dispatched 1D grid:
//   [0, 1728): wqkv [768][2304] -> WqkvT [2304][768] bf16
//   [1728, 2304): wproj [768][768] -> WprojT [768][768]^T bf16
//   [2304, 2336): biases (f32) + mask bias
__global__ void k_prep(const void* wqkv, const void* wproj,
                       const void* bqkv, const void* bproj, const void* mask,
                       unsigned short* WqkvT, unsigned short* WprojT,
                       float* bqkvF, float* bprojF, float* maskF) {
    __shared__ float tile[32][33];
    int id = blockIdx.x;
    if (id < 2304) {
        const void* src; unsigned short* dst; int K = C_, N, bx, by;
        if (id < 1728) { src = wqkv; dst = WqkvT; N = C3_; bx = id % 72; by = id / 72; }
        else { id -= 1728; src = wproj; dst = WprojT; N = C_; bx = id % 24; by = id / 24; }
        int mode = detect_bf16(src);
        int n0 = bx * 32, k0 = by * 32;
        int tx = threadIdx.x & 31, ty = threadIdx.x >> 5;
        for (int r = ty; r < 32; r += 8) {
            size_t idx = (size_t)(k0 + r) * N + (n0 + tx);
            tile[r][tx] = mode ? bf2f(((const unsigned short*)src)[idx])
                               : ((const float*)src)[idx];
        }
        __syncthreads();
        for (int r = ty; r < 32; r += 8)
            dst[(size_t)(n0 + r) * K + k0 + tx] = f2bf(tile[tx][r]);
    } else {
        int i = (id - 2304) * 256 + threadIdx.x;
        if (i < C3_) bqkvF[i] = ldf(bqkv, i, detect_bf16(bqkv));
        if (i < C_)  bprojF[i] = ldf(bproj, i, detect_bf16(bproj));
        if (i < BT_) {
            int mm = detect_mask(mask);
            int mv;
            if (mm == 1)      mv = ((const int*)mask)[i] != 0;
            else if (mm == 2) mv = ((const float*)mask)[i] != 0.0f;
            else              mv = ((const unsigned char*)mask)[i] != 0;
            maskF[i] = mv ? FMIN_ : 0.0f;
        }
    }
}

// ---------------- bf16 MFMA GEMM: C = A[M][K] * Bt[N][K]^T + bias ----------------
// Staging via global_load_lds (16B/lane DMA) with BOTH-SIDES XOR swizzle:
// LDS dest linear, global source 16B-slot pre-swizzled by ^(row&7),
// ds_read slot ^(row&7) -> conflict-free fragment reads.
// EPI 0: scatter into Q([B,H,T,D], *QSCALE), K([B,H,T,D]), V^T([B,H,D,T]), bf16
// EPI 1: f32 [M][N] into d_out
template<int EPI>
__global__ __launch_bounds__(256) void k_gemm(
        const unsigned short* __restrict__ A, const unsigned short* __restrict__ Bt,
        const float* __restrict__ bias,
        void* __restrict__ out0, unsigned short* __restrict__ out1,
        unsigned short* __restrict__ out2,
        int M, int N, int K) {
    __shared__ __align__(16) unsigned short la[128*64];
    __shared__ __align__(16) unsigned short lb[128*64];
    const int tid = threadIdx.x;
    const int w = tid >> 6, lane = tid & 63, lr = lane & 15, lg = lane >> 4;
    const int wm = (w >> 1) * 64, wn = (w & 1) * 64;
    const int n0 = blockIdx.x * 128, m0 = blockIdx.y * 128;
    const int rin = lane >> 3;
    const int gslot = (lane & 7) ^ rin;     // pre-swizzled global 16B-slot
    f32x4 acc[4][4] = {};
    for (int k0 = 0; k0 < K; k0 += 64) {
#pragma unroll
        for (int c = 0; c < 4; ++c) {
            const int chunk = w * 4 + c;
            const int row = chunk * 8 + rin;
            GLDS16(&A[(size_t)(m0+row)*K + k0 + gslot*8], &la[chunk*512]);
            GLDS16(&Bt[(size_t)(n0+row)*K + k0 + gslot*8], &lb[chunk*512]);
        }
        __syncthreads();   // implicit vmcnt(0) drains the DMA
#pragma unroll
        for (int ks = 0; ks < 64; ks += 32) {
            short8 af[4], bfr[4];
            const int rs = (lg + (ks >> 3)) ^ (lr & 7);   // swizzled read slot
#pragma unroll
            for (int i = 0; i < 4; ++i)
                af[i] = *(const short8*)&la[(wm + i*16 + lr)*64 + rs*8];
#pragma unroll
            for (int j = 0; j < 4; ++j)
                bfr[j] = *(const short8*)&lb[(wn + j*16 + lr)*64 + rs*8];
#pragma unroll
            for (int i = 0; i < 4; ++i)
#pragma unroll
                for (int j = 0; j < 4; ++j)
                    acc[i][j] = __builtin_amdgcn_mfma_f32_16x16x32_bf16(af[i], bfr[j], acc[i][j], 0, 0, 0);
        }
        __syncthreads();   // all reads done before next-tile DMA
    }
#pragma unroll
    for (int i = 0; i < 4; ++i)
#pragma unroll
        for (int j = 0; j < 4; ++j)
#pragma unroll
            for (int r = 0; r < 4; ++r) {
                int row = m0 + wm + i*16 + lg*4 + r;
                int col = n0 + wn + j*16 + lr;
                float v = acc[i][j][r] + bias[col];
                if (EPI == 0) {
                    int seg = col / C_;
                    int c = col - seg * C_;
                    int h = c >> 6, d = c & 63;
                    int b = row >> 11, t = row & (T_ - 1);
                    if (seg == 0)      ((unsigned short*)out0)[(((size_t)b*H_ + h)*T_ + t)*D_ + d] = f2bf(v * QSCALE_);
                    else if (seg == 1) out1[(((size_t)b*H_ + h)*T_ + t)*D_ + d] = f2bf(v);
                    else               out2[(((size_t)b*H_ + h)*D_ + d)*T_ + t] = f2bf(v);
                } else {
                    ((float*)out0)[(size_t)row * N + col] = v;
                }
            }
}

// ---------------- flash attention, swapped QK^T, log2-domain softmax ----------------
// QBLK=64 (2 waves x 32 q-rows), grid = 48 bh x 32 qt = 1536 blocks ->
// 6 blocks/CU x 2 waves = 12 waves/CU (was 3x4 at 768 blocks, occupancy-capped).
// Q[B,H,T,D] (pre-scaled by 0.125*log2e), K[B,H,T,D], V^T[B,H,D,T], all bf16.
// S^T = mfma(A=K, B=Q) with C initialized to the per-key mask bias (0 / -FLT_MAX).
// Softmax in log2 domain; defer-max THR=8 (p <= 2^8).
// PV slot-relabeled contraction (P packs in-lane via cvt_pk; V 2x ds_read_b64).
// O accumulates transposed: O^T[d][q], col=q=lr -> rescale lane-uniform.
__global__ __launch_bounds__(128) void k_attn(
        const unsigned short* __restrict__ Q, const unsigned short* __restrict__ Kt,
        const unsigned short* __restrict__ Vt, const float* __restrict__ maskF,
        unsigned short* __restrict__ AO) {
    __shared__ __align__(16) unsigned short lk[64*72];
    __shared__ __align__(16) unsigned short lv[64*72];
    __shared__ __align__(16) float lmb[64];
    const int tid = threadIdx.x;
    const int w = tid >> 6, lane = tid & 63, lr = lane & 15, lg = lane >> 4;
    // bijective XCD swizzle: 1536 blocks = 8 XCD x 192; 32 consecutive share one bh's K/V
    const int per = gridDim.x >> 3;
    const int swz = (blockIdx.x & 7) * per + (blockIdx.x >> 3);
    const int bh = swz >> 5, qt = swz & 31;
    const int b = bh / H_, h = bh - b * H_;
    const int qbase = qt * 64 + w * 32;
    const unsigned short* Qb = Q  + (size_t)bh * T_ * D_;
    const unsigned short* Kb = Kt + (size_t)bh * T_ * D_;
    const unsigned short* Vb = Vt + (size_t)bh * D_ * T_;

    // Q as B-operand: lane holds col q=qc*16+lr, k-elems d = dh*32+lg*8..+7
    short8 qf[2][2];
#pragma unroll
    for (int qc = 0; qc < 2; ++qc)
#pragma unroll
        for (int dh = 0; dh < 2; ++dh)
            qf[qc][dh] = *(const short8*)&Qb[(size_t)(qbase + qc*16 + lr) * D_ + dh*32 + lg*8];

    f32x4 ot[4][2] = {};           // O^T[dblk][qc]
    float m[2] = {-INFINITY, -INFINITY}, l[2] = {0.0f, 0.0f};

    for (int kt = 0; kt < T_; kt += 64) {
#pragma unroll
        for (int c = 0; c < 4; ++c) {
            int idx = tid + c * 128;
            int row = idx >> 3, c8 = (idx & 7) * 8;
            *(short8*)&lk[row*72 + c8] = *(const short8*)&Kb[(size_t)(kt + row)*D_ + c8];
            *(short8*)&lv[row*72 + c8] = *(const short8*)&Vb[(size_t)row * T_ + kt + c8];
        }
        if (tid < 64) lmb[tid] = maskF[b*T_ + kt + tid];
        __syncthreads();

        // C-init = mask bias per key (shared by both qc); mask add is free+exact
        f32x4 st[4][2];
#pragma unroll
        for (int kf = 0; kf < 4; ++kf) {
            f32x4 mi = *(const f32x4*)&lmb[kf*16 + lg*4];
            st[kf][0] = mi;
            st[kf][1] = mi;
        }
        // S^T = K Q^T + mask
#pragma unroll
        for (int dh = 0; dh < 2; ++dh) {
            short8 kfr[4];
#pragma unroll
            for (int kf = 0; kf < 4; ++kf)
                kfr[kf] = *(const short8*)&lk[(kf*16 + lr)*72 + dh*32 + lg*8];
#pragma unroll
            for (int kf = 0; kf < 4; ++kf)
#pragma unroll
                for (int qc = 0; qc < 2; ++qc)
                    st[kf][qc] = __builtin_amdgcn_mfma_f32_16x16x32_bf16(kfr[kf], qf[qc][dh], st[kf][qc], 0, 0, 0);
        }
        // online softmax per qc (row = q = qc*16+lr; spread over 4 lanes lg)
#pragma unroll
        for (int qc = 0; qc < 2; ++qc) {
            float t0 = fmaxf(fmaxf(st[0][qc][0], st[0][qc][1]), st[0][qc][2]);
            float t1 = fmaxf(fmaxf(st[0][qc][3], st[1][qc][0]), st[1][qc][1]);
            float t2 = fmaxf(fmaxf(st[1][qc][2], st[1][qc][3]), st[2][qc][0]);
            float t3 = fmaxf(fmaxf(st[2][qc][1], st[2][qc][2]), st[2][qc][3]);
            float t4 = fmaxf(fmaxf(st[3][qc][0], st[3][qc][1]), st[3][qc][2]);
            float tm = fmaxf(fmaxf(t0, t1), fmaxf(fmaxf(t2, t3), fmaxf(t4, st[3][qc][3])));
            tm = fmaxf(tm, __shfl_xor(tm, 16));
            tm = fmaxf(tm, __shfl_xor(tm, 32));
            // defer-max: skip rescale while max growth <= 8 (p bounded by 2^8)
            if (!__all(tm - m[qc] <= 8.0f)) {
                float mn = fmaxf(m[qc], tm);
                float sc = __builtin_amdgcn_exp2f(m[qc] - mn);
                m[qc] = mn;
                l[qc] *= sc;
#pragma unroll
                for (int dblk = 0; dblk < 4; ++dblk) ot[dblk][qc] *= sc;
            }
            float mr = m[qc];
            float ps = 0.0f;
#pragma unroll
            for (int kf = 0; kf < 4; ++kf)
#pragma unroll
                for (int r = 0; r < 4; ++r) {
                    float p = __builtin_amdgcn_exp2f(st[kf][qc][r] - mr);
                    st[kf][qc][r] = p;
                    ps += p;
                }
            l[qc] += ps;
        }
        // pack P in-lane into relabeled B-fragments: pb[qc][ks]
        union PU { unsigned int u[4]; short8 s; };
        PU pb[2][2];
#pragma unroll
        for (int qc = 0; qc < 2; ++qc)
#pragma unroll
            for (int ks = 0; ks < 2; ++ks) {
                pb[qc][ks].u[0] = cvtpk(st[2*ks][qc][0],   st[2*ks][qc][1]);
                pb[qc][ks].u[1] = cvtpk(st[2*ks][qc][2],   st[2*ks][qc][3]);
                pb[qc][ks].u[2] = cvtpk(st[2*ks+1][qc][0], st[2*ks+1][qc][1]);
                pb[qc][ks].u[3] = cvtpk(st[2*ks+1][qc][2], st[2*ks+1][qc][3]);
            }
        // O^T += V^T P^T with matching slot relabel: A-slot (ks,j):
        //   j=0..3 -> key 32ks+lg*4+j ; j=4..7 -> key 32ks+16+lg*4+(j-4)
#pragma unroll
        for (int ks = 0; ks < 2; ++ks)
#pragma unroll
            for (int dblk = 0; dblk < 4; ++dblk) {
                const int rb = (dblk*16 + lr)*72 + 32*ks + lg*4;
                s16x4 lo = *(const s16x4*)&lv[rb];
                s16x4 hi = *(const s16x4*)&lv[rb + 16];
                short8 va;
                va[0]=lo[0]; va[1]=lo[1]; va[2]=lo[2]; va[3]=lo[3];
                va[4]=hi[0]; va[5]=hi[1]; va[6]=hi[2]; va[7]=hi[3];
#pragma unroll
                for (int qc = 0; qc < 2; ++qc)
                    ot[dblk][qc] = __builtin_amdgcn_mfma_f32_16x16x32_bf16(va, pb[qc][ks].s, ot[dblk][qc], 0, 0, 0);
            }
        __syncthreads();
    }
    // epilogue: reduce l across lg, normalize, store O^T -> AO rows
#pragma unroll
    for (int qc = 0; qc < 2; ++qc) {
        float ls = l[qc];
        ls += __shfl_xor(ls, 16);
        ls += __shfl_xor(ls, 32);
        float inv = 1.0f / ls;
        size_t row = (size_t)b*T_ + qbase + qc*16 + lr;
#pragma unroll
        for (int dblk = 0; dblk < 4; ++dblk) {
            unsigned int w0 = cvtpk(ot[dblk][qc][0]*inv, ot[dblk][qc][1]*inv);
            unsigned int w1 = cvtpk(ot[dblk][qc][2]*inv, ot[dblk][qc][3]*inv);
            uint2 pkd; pkd.x = w0; pkd.y = w1;
            *(uint2*)&AO[row * C_ + h*64 + dblk*16 + lg*4] = pkd;
        }
    }
}

extern "C" void kernel_launch(void* const* d_in, const int* in_sizes, int n_in,
                              void* d_out, int out_size, void* d_ws, size_t ws_size,
                              hipStream_t stream) {
    const void* x     = d_in[0];
    const void* mask  = d_in[1];
    const void* wqkv  = d_in[2];
    const void* bqkv  = d_in[3];
    const void* wproj = d_in[4];
    const void* bproj = d_in[5];

    char* ws = (char*)d_ws;
    size_t off = 0;
    auto alloc = [&](size_t bytes) -> void* {
        void* p = ws + off;
        off = (off + bytes + 255) & ~(size_t)255;
        return p;
    };
    unsigned short* Xb    = (unsigned short*)alloc((size_t)BT_ * C_ * 2);
    unsigned short* WqkvT = (unsigned short*)alloc((size_t)C3_ * C_ * 2);
    unsigned short* WprojT= (unsigned short*)alloc((size_t)C_ * C_ * 2);
    float* bqkvF          = (float*)alloc((size_t)C3_ * 4);
    float* bprojF         = (float*)alloc((size_t)C_ * 4);
    float* maskF          = (float*)alloc((size_t)BT_ * 4);
    unsigned short* Qs    = (unsigned short*)alloc((size_t)B_*H_*T_*D_ * 2);
    unsigned short* Ks    = (unsigned short*)alloc((size_t)B_*H_*T_*D_ * 2);
    unsigned short* Vts   = (unsigned short*)alloc((size_t)B_*H_*T_*D_ * 2);
    unsigned short* AO    = (unsigned short*)alloc((size_t)BT_ * C_ * 2);

    k_canon_x<<<(BT_*C_/8 + 255)/256, 256, 0, stream>>>(x, Xb);
    k_prep<<<2336, 256, 0, stream>>>(wqkv, wproj, bqkv, bproj, mask,
                                     WqkvT, WprojT, bqkvF, bprojF, maskF);

    // QKV projection -> Q(,K)(,V^T)
    k_gemm<0><<<dim3(C3_/128, BT_/128), 256, 0, stream>>>(
        Xb, WqkvT, bqkvF, Qs, Ks, Vts, BT_, C3_, C_);
    // flash attention (swapped QK^T, log2 softmax, QBLK=64 / 2-wave blocks)
    k_attn<<<B_*H_*(T_/64), 128, 0, stream>>>(Qs, Ks, Vts, maskF, AO);
    // output projection -> f32 d_out
    k_gemm<1><<<dim3(C_/128, BT_/128), 256, 0, stream>>>(
        AO, WprojT, bprojF, d_out, nullptr, nullptr, BT_, C_, C_);
}

// Round 10
// 163.630 us; speedup vs baseline: 1.9125x; 1.9125x over previous
//
#include <hip/hip_runtime.h>
#include <stdint.h>

#define B_ 4
#define T_ 2048
#define C_ 768
#define H_ 12
#define D_ 64
#define BT_ (B_*T_)
#define C3_ (3*C_)
#define FMIN_ (-3.402823466e38f)
// 0.125 * log2(e): Q prescale so QK^T scores are in log2 units
#define QSCALE_ (0.18033688f)

typedef __attribute__((ext_vector_type(8))) short short8;
typedef __attribute__((ext_vector_type(4))) short s16x4;
typedef __attribute__((ext_vector_type(4))) float f32x4;

// async global->LDS DMA, 16B per lane; LDS dest = wave-uniform base + lane*16
#define GLDS16(g, l) __builtin_amdgcn_global_load_lds( \
    (const __attribute__((address_space(1))) void*)(g), \
    (__attribute__((address_space(3))) void*)(l), 16, 0, 0)

__device__ __forceinline__ float bf2f(unsigned short u) {
    union { unsigned int i; float f; } v; v.i = ((unsigned int)u) << 16; return v.f;
}
__device__ __forceinline__ unsigned short f2bf(float f) {
    union { float ff; unsigned int i; } v; v.ff = f;
    unsigned int r = v.i + 0x7fffu + ((v.i >> 16) & 1u);
    return (unsigned short)(r >> 16);
}
// packed f32x2 -> bf16x2 (RNE), single HW instr
__device__ __forceinline__ unsigned int cvtpk(float lo, float hi) {
    unsigned int r;
    asm("v_cvt_pk_bf16_f32 %0, %1, %2" : "=v"(r) : "v"(lo), "v"(hi));
    return r;
}
__device__ __forceinline__ float ldf(const void* p, size_t i, int isbf) {
    return isbf ? bf2f(((const unsigned short*)p)[i]) : ((const float*)p)[i];
}

// ---------------- wave-level self-detection ----------------
// bf16 vs f32: even 16-bit words of bf16 data have exponent clustered ~118..132;
// f32 low-mantissa halves are ~uniform. 64 samples, threshold 32: P(err)~1e-8.
__device__ __forceinline__ int detect_bf16(const void* p) {
    unsigned short u = ((const unsigned short*)p)[2 * (threadIdx.x & 63)];
    int e = (u >> 7) & 0xff;
    unsigned long long m = __ballot(e >= 100 && e <= 140);
    return __popcll(m) >= 32;
}
// mask mode: 1=int32 (all dwords 0/1), 2=f32 (all 0.0/1.0), 0=uint8/bool
__device__ __forceinline__ int detect_mask(const void* p) {
    unsigned int d = ((const unsigned int*)p)[threadIdx.x & 63];
    unsigned long long bi = __ballot(d <= 1u);
    unsigned long long bf = __ballot(d == 0u || d == 0x3f800000u);
    if (__popcll(bi) == 64) return 1;
    if (__popcll(bf) == 64) return 2;
    return 0;
}

// ---------------- merged prep: x-canon + both weight transposes + biases + mask ----
// range-dispatched 1D grid (5408 blocks x 256):
//   [0, 3072):     x [8192][768] -> bf16 Xb (8 elems/thread)
//   [3072, 4800):  wqkv [768][2304] -> WqkvT [2304][768] bf16
//   [4800, 5376):  wproj [768][768] -> WprojT^T bf16
//   [5376, 5408):  biases (f32) + mask bias
__global__ void k_prep(const void* x, const void* wqkv, const void* wproj,
                       const void* bqkv, const void* bproj, const void* mask,
                       unsigned short* Xb, unsigned short* WqkvT, unsigned short* WprojT,
                       float* bqkvF, float* bprojF, float* maskF) {
    __shared__ float tile[32][33];
    int id = blockIdx.x;
    if (id < 3072) {
        int i = id * 256 + threadIdx.x;     // short8 index, exact coverage
        if (detect_bf16(x)) {
            ((int4*)Xb)[i] = ((const int4*)x)[i];
        } else {
            const float4* xf = (const float4*)x;
            float4 a = xf[2*i], b = xf[2*i+1];
            short8 o;
            o[0]=(short)f2bf(a.x); o[1]=(short)f2bf(a.y); o[2]=(short)f2bf(a.z); o[3]=(short)f2bf(a.w);
            o[4]=(short)f2bf(b.x); o[5]=(short)f2bf(b.y); o[6]=(short)f2bf(b.z); o[7]=(short)f2bf(b.w);
            *(short8*)&Xb[8*i] = o;
        }
    } else if (id < 5376) {
        id -= 3072;
        const void* src; unsigned short* dst; int K = C_, N, bx, by;
        if (id < 1728) { src = wqkv; dst = WqkvT; N = C3_; bx = id % 72; by = id / 72; }
        else { id -= 1728; src = wproj; dst = WprojT; N = C_; bx = id % 24; by = id / 24; }
        int mode = detect_bf16(src);
        int n0 = bx * 32, k0 = by * 32;
        int tx = threadIdx.x & 31, ty = threadIdx.x >> 5;
        for (int r = ty; r < 32; r += 8) {
            size_t idx = (size_t)(k0 + r) * N + (n0 + tx);
            tile[r][tx] = mode ? bf2f(((const unsigned short*)src)[idx])
                               : ((const float*)src)[idx];
        }
        __syncthreads();
        for (int r = ty; r < 32; r += 8)
            dst[(size_t)(n0 + r) * K + k0 + tx] = f2bf(tile[tx][r]);
    } else {
        int i = (id - 5376) * 256 + threadIdx.x;
        if (i < C3_) bqkvF[i] = ldf(bqkv, i, detect_bf16(bqkv));
        if (i < C_)  bprojF[i] = ldf(bproj, i, detect_bf16(bproj));
        if (i < BT_) {
            int mm = detect_mask(mask);
            int mv;
            if (mm == 1)      mv = ((const int*)mask)[i] != 0;
            else if (mm == 2) mv = ((const float*)mask)[i] != 0.0f;
            else              mv = ((const unsigned char*)mask)[i] != 0;
            maskF[i] = mv ? FMIN_ : 0.0f;
        }
    }
}

// ---------------- bf16 MFMA GEMM: C = A[M][K] * Bt[N][K]^T + bias ----------------
// Staging via global_load_lds (16B/lane DMA) with BOTH-SIDES XOR swizzle:
// LDS dest linear, global source 16B-slot pre-swizzled by ^(row&7),
// ds_read slot ^(row&7) -> conflict-free fragment reads.
// EPI 0: scatter Q([B,H,T,D], *QSCALE) / K([B,H,T,D]) scalar;
//        V^T([B,H,D,T]) via LDS-transpose -> 16B coalesced t-runs.
// EPI 1: f32 [M][N] into d_out
template<int EPI>
__global__ __launch_bounds__(256) void k_gemm(
        const unsigned short* __restrict__ A, const unsigned short* __restrict__ Bt,
        const float* __restrict__ bias,
        void* __restrict__ out0, unsigned short* __restrict__ out1,
        unsigned short* __restrict__ out2,
        int M, int N, int K) {
    __shared__ __align__(16) unsigned short smem[2*128*64];   // la | lb ; tr alias
    unsigned short* la = smem;
    unsigned short* lb = smem + 128*64;
    const int tid = threadIdx.x;
    const int w = tid >> 6, lane = tid & 63, lr = lane & 15, lg = lane >> 4;
    const int wm = (w >> 1) * 64, wn = (w & 1) * 64;
    const int n0 = blockIdx.x * 128, m0 = blockIdx.y * 128;
    const int rin = lane >> 3;
    const int gslot = (lane & 7) ^ rin;     // pre-swizzled global 16B-slot
    f32x4 acc[4][4] = {};
    for (int k0 = 0; k0 < K; k0 += 64) {
#pragma unroll
        for (int c = 0; c < 4; ++c) {
            const int chunk = w * 4 + c;
            const int row = chunk * 8 + rin;
            GLDS16(&A[(size_t)(m0+row)*K + k0 + gslot*8], &la[chunk*512]);
            GLDS16(&Bt[(size_t)(n0+row)*K + k0 + gslot*8], &lb[chunk*512]);
        }
        __syncthreads();   // implicit vmcnt(0) drains the DMA
#pragma unroll
        for (int ks = 0; ks < 64; ks += 32) {
            short8 af[4], bfr[4];
            const int rs = (lg + (ks >> 3)) ^ (lr & 7);   // swizzled read slot
#pragma unroll
            for (int i = 0; i < 4; ++i)
                af[i] = *(const short8*)&la[(wm + i*16 + lr)*64 + rs*8];
#pragma unroll
            for (int j = 0; j < 4; ++j)
                bfr[j] = *(const short8*)&lb[(wn + j*16 + lr)*64 + rs*8];
#pragma unroll
            for (int i = 0; i < 4; ++i)
#pragma unroll
                for (int j = 0; j < 4; ++j)
                    acc[i][j] = __builtin_amdgcn_mfma_f32_16x16x32_bf16(af[i], bfr[j], acc[i][j], 0, 0, 0);
        }
        __syncthreads();   // all reads done before next-tile DMA (also frees smem)
    }
    if (EPI == 1) {
#pragma unroll
        for (int i = 0; i < 4; ++i)
#pragma unroll
            for (int j = 0; j < 4; ++j)
#pragma unroll
                for (int r = 0; r < 4; ++r) {
                    int row = m0 + wm + i*16 + lg*4 + r;
                    int col = n0 + wn + j*16 + lr;
                    ((float*)out0)[(size_t)row * N + col] = acc[i][j][r] + bias[col];
                }
        return;
    }
    // EPI 0: segment is block-uniform (n0 multiple of 128; boundaries 768/1536)
    const int seg0 = n0 / C_;
    if (seg0 < 2) {
        // Q or K: scalar scatter (d-consecutive across lr -> 32B runs)
#pragma unroll
        for (int i = 0; i < 4; ++i)
#pragma unroll
            for (int j = 0; j < 4; ++j)
#pragma unroll
                for (int r = 0; r < 4; ++r) {
                    int row = m0 + wm + i*16 + lg*4 + r;
                    int col = n0 + wn + j*16 + lr;
                    float v = acc[i][j][r] + bias[col];
                    int c = col - seg0 * C_;
                    int h = c >> 6, d = c & 63;
                    int b = row >> 11, t = row & (T_ - 1);
                    size_t idx = (((size_t)b*H_ + h)*T_ + t)*D_ + d;
                    if (seg0 == 0) ((unsigned short*)out0)[idx] = f2bf(v * QSCALE_);
                    else           out1[idx] = f2bf(v);
                }
    } else {
        // V block: transpose through LDS (reuse smem), store 16B t-contiguous runs.
        unsigned short* tr = smem;           // [64 cols][136 rows] bf16 = 17408 B
        const int bidx = m0 >> 11;
        const int tbase = m0 & (T_ - 1);
#pragma unroll
        for (int p = 0; p < 2; ++p) {
            if ((w & 1) == p) {              // waves with wn == 64*p own these cols
#pragma unroll
                for (int i = 0; i < 4; ++i)
#pragma unroll
                    for (int j = 0; j < 4; ++j)
#pragma unroll
                        for (int r = 0; r < 4; ++r) {
                            int col = n0 + wn + j*16 + lr;
                            float v = acc[i][j][r] + bias[col];
                            tr[(j*16 + lr)*136 + wm + i*16 + lg*4 + r] = f2bf(v);
                        }
            }
            __syncthreads();
            {
                int lc = tid >> 2, k4 = tid & 3;       // col-local, chunk phase
                int c = n0 + p*64 + lc - 2*C_;         // V-local col in [0, 768)
                int h = c >> 6, d = c & 63;
                unsigned short* dst = out2 + (((size_t)bidx*H_ + h)*D_ + d)*T_ + tbase;
#pragma unroll
                for (int s = 0; s < 4; ++s) {
                    int t0 = (k4 + s*4) * 8;
                    *(short8*)&dst[t0] = *(const short8*)&tr[lc*136 + t0];
                }
            }
            __syncthreads();
        }
    }
}

// ---------------- flash attention, swapped QK^T, log2-domain softmax ----------------
// (round-8 proven structure: QBLK=128, 4 waves, single-buffer, two barriers/tile)
// Q[B,H,T,D] (pre-scaled by 0.125*log2e), K[B,H,T,D], V^T[B,H,D,T], all bf16.
// S^T = mfma(A=K, B=Q) with C initialized to the per-key mask bias (0 / -FLT_MAX).
// Softmax in log2 domain; defer-max THR=8 (p <= 2^8).
// PV slot-relabeled contraction (P packs in-lane via cvt_pk; V 2x ds_read_b64).
// O accumulates transposed: O^T[d][q], col=q=lr -> rescale lane-uniform.
__global__ __launch_bounds__(256) void k_attn(
        const unsigned short* __restrict__ Q, const unsigned short* __restrict__ Kt,
        const unsigned short* __restrict__ Vt, const float* __restrict__ maskF,
        unsigned short* __restrict__ AO) {
    __shared__ __align__(16) unsigned short lk[64*72];
    __shared__ __align__(16) unsigned short lv[64*72];
    __shared__ __align__(16) float lmb[64];
    const int tid = threadIdx.x;
    const int w = tid >> 6, lane = tid & 63, lr = lane & 15, lg = lane >> 4;
    // bijective XCD swizzle: 768 blocks = 8 XCD x 96; 16 consecutive share one bh's K/V
    const int per = gridDim.x >> 3;
    const int swz = (blockIdx.x & 7) * per + (blockIdx.x >> 3);
    const int bh = swz >> 4, qt = swz & 15;
    const int b = bh / H_, h = bh - b * H_;
    const int qbase = qt * 128 + w * 32;
    const unsigned short* Qb = Q  + (size_t)bh * T_ * D_;
    const unsigned short* Kb = Kt + (size_t)bh * T_ * D_;
    const unsigned short* Vb = Vt + (size_t)bh * D_ * T_;

    // Q as B-operand: lane holds col q=qc*16+lr, k-elems d = dh*32+lg*8..+7
    short8 qf[2][2];
#pragma unroll
    for (int qc = 0; qc < 2; ++qc)
#pragma unroll
        for (int dh = 0; dh < 2; ++dh)
            qf[qc][dh] = *(const short8*)&Qb[(size_t)(qbase + qc*16 + lr) * D_ + dh*32 + lg*8];

    f32x4 ot[4][2] = {};           // O^T[dblk][qc]
    float m[2] = {-INFINITY, -INFINITY}, l[2] = {0.0f, 0.0f};

    for (int kt = 0; kt < T_; kt += 64) {
#pragma unroll
        for (int c = 0; c < 2; ++c) {
            int idx = tid + c * 256;
            int row = idx >> 3, c8 = (idx & 7) * 8;
            *(short8*)&lk[row*72 + c8] = *(const short8*)&Kb[(size_t)(kt + row)*D_ + c8];
            *(short8*)&lv[row*72 + c8] = *(const short8*)&Vb[(size_t)row * T_ + kt + c8];
        }
        if (tid < 64) lmb[tid] = maskF[b*T_ + kt + tid];
        __syncthreads();

        // C-init = mask bias per key (shared by both qc); mask add is free+exact
        f32x4 st[4][2];
#pragma unroll
        for (int kf = 0; kf < 4; ++kf) {
            f32x4 mi = *(const f32x4*)&lmb[kf*16 + lg*4];
            st[kf][0] = mi;
            st[kf][1] = mi;
        }
        // S^T = K Q^T + mask
#pragma unroll
        for (int dh = 0; dh < 2; ++dh) {
            short8 kfr[4];
#pragma unroll
            for (int kf = 0; kf < 4; ++kf)
                kfr[kf] = *(const short8*)&lk[(kf*16 + lr)*72 + dh*32 + lg*8];
#pragma unroll
            for (int kf = 0; kf < 4; ++kf)
#pragma unroll
                for (int qc = 0; qc < 2; ++qc)
                    st[kf][qc] = __builtin_amdgcn_mfma_f32_16x16x32_bf16(kfr[kf], qf[qc][dh], st[kf][qc], 0, 0, 0);
        }
        // online softmax per qc (row = q = qc*16+lr; spread over 4 lanes lg)
#pragma unroll
        for (int qc = 0; qc < 2; ++qc) {
            float t0 = fmaxf(fmaxf(st[0][qc][0], st[0][qc][1]), st[0][qc][2]);
            float t1 = fmaxf(fmaxf(st[0][qc][3], st[1][qc][0]), st[1][qc][1]);
            float t2 = fmaxf(fmaxf(st[1][qc][2], st[1][qc][3]), st[2][qc][0]);
            float t3 = fmaxf(fmaxf(st[2][qc][1], st[2][qc][2]), st[2][qc][3]);
            float t4 = fmaxf(fmaxf(st[3][qc][0], st[3][qc][1]), st[3][qc][2]);
            float tm = fmaxf(fmaxf(t0, t1), fmaxf(fmaxf(t2, t3), fmaxf(t4, st[3][qc][3])));
            tm = fmaxf(tm, __shfl_xor(tm, 16));
            tm = fmaxf(tm, __shfl_xor(tm, 32));
            // defer-max: skip rescale while max growth <= 8 (p bounded by 2^8)
            if (!__all(tm - m[qc] <= 8.0f)) {
                float mn = fmaxf(m[qc], tm);
                float sc = __builtin_amdgcn_exp2f(m[qc] - mn);
                m[qc] = mn;
                l[qc] *= sc;
#pragma unroll
                for (int dblk = 0; dblk < 4; ++dblk) ot[dblk][qc] *= sc;
            }
            float mr = m[qc];
            float ps = 0.0f;
#pragma unroll
            for (int kf = 0; kf < 4; ++kf)
#pragma unroll
                for (int r = 0; r < 4; ++r) {
                    float p = __builtin_amdgcn_exp2f(st[kf][qc][r] - mr);
                    st[kf][qc][r] = p;
                    ps += p;
                }
            l[qc] += ps;
        }
        // pack P in-lane into relabeled B-fragments: pb[qc][ks]
        union PU { unsigned int u[4]; short8 s; };
        PU pb[2][2];
#pragma unroll
        for (int qc = 0; qc < 2; ++qc)
#pragma unroll
            for (int ks = 0; ks < 2; ++ks) {
                pb[qc][ks].u[0] = cvtpk(st[2*ks][qc][0],   st[2*ks][qc][1]);
                pb[qc][ks].u[1] = cvtpk(st[2*ks][qc][2],   st[2*ks][qc][3]);
                pb[qc][ks].u[2] = cvtpk(st[2*ks+1][qc][0], st[2*ks+1][qc][1]);
                pb[qc][ks].u[3] = cvtpk(st[2*ks+1][qc][2], st[2*ks+1][qc][3]);
            }
        // O^T += V^T P^T with matching slot relabel: A-slot (ks,j):
        //   j=0..3 -> key 32ks+lg*4+j ; j=4..7 -> key 32ks+16+lg*4+(j-4)
#pragma unroll
        for (int ks = 0; ks < 2; ++ks)
#pragma unroll
            for (int dblk = 0; dblk < 4; ++dblk) {
                const int rb = (dblk*16 + lr)*72 + 32*ks + lg*4;
                s16x4 lo = *(const s16x4*)&lv[rb];
                s16x4 hi = *(const s16x4*)&lv[rb + 16];
                short8 va;
                va[0]=lo[0]; va[1]=lo[1]; va[2]=lo[2]; va[3]=lo[3];
                va[4]=hi[0]; va[5]=hi[1]; va[6]=hi[2]; va[7]=hi[3];
#pragma unroll
                for (int qc = 0; qc < 2; ++qc)
                    ot[dblk][qc] = __builtin_amdgcn_mfma_f32_16x16x32_bf16(va, pb[qc][ks].s, ot[dblk][qc], 0, 0, 0);
            }
        __syncthreads();
    }
    // epilogue: reduce l across lg, normalize, store O^T -> AO rows
#pragma unroll
    for (int qc = 0; qc < 2; ++qc) {
        float ls = l[qc];
        ls += __shfl_xor(ls, 16);
        ls += __shfl_xor(ls, 32);
        float inv = 1.0f / ls;
        size_t row = (size_t)b*T_ + qbase + qc*16 + lr;
#pragma unroll
        for (int dblk = 0; dblk < 4; ++dblk) {
            unsigned int w0 = cvtpk(ot[dblk][qc][0]*inv, ot[dblk][qc][1]*inv);
            unsigned int w1 = cvtpk(ot[dblk][qc][2]*inv, ot[dblk][qc][3]*inv);
            uint2 pkd; pkd.x = w0; pkd.y = w1;
            *(uint2*)&AO[row * C_ + h*64 + dblk*16 + lg*4] = pkd;
        }
    }
}

extern "C" void kernel_launch(void* const* d_in, const int* in_sizes, int n_in,
                              void* d_out, int out_size, void* d_ws, size_t ws_size,
                              hipStream_t stream) {
    const void* x     = d_in[0];
    const void* mask  = d_in[1];
    const void* wqkv  = d_in[2];
    const void* bqkv  = d_in[3];
    const void* wproj = d_in[4];
    const void* bproj = d_in[5];

    char* ws = (char*)d_ws;
    size_t off = 0;
    auto alloc = [&](size_t bytes) -> void* {
        void* p = ws + off;
        off = (off + bytes + 255) & ~(size_t)255;
        return p;
    };
    unsigned short* Xb    = (unsigned short*)alloc((size_t)BT_ * C_ * 2);
    unsigned short* WqkvT = (unsigned short*)alloc((size_t)C3_ * C_ * 2);
    unsigned short* WprojT= (unsigned short*)alloc((size_t)C_ * C_ * 2);
    float* bqkvF          = (float*)alloc((size_t)C3_ * 4);
    float* bprojF         = (float*)alloc((size_t)C_ * 4);
    float* maskF          = (float*)alloc((size_t)BT_ * 4);
    unsigned short* Qs    = (unsigned short*)alloc((size_t)B_*H_*T_*D_ * 2);
    unsigned short* Ks    = (unsigned short*)alloc((size_t)B_*H_*T_*D_ * 2);
    unsigned short* Vts   = (unsigned short*)alloc((size_t)B_*H_*T_*D_ * 2);
    unsigned short* AO    = (unsigned short*)alloc((size_t)BT_ * C_ * 2);

    // merged prep: x-canon + weight transposes + biases + mask
    k_prep<<<5408, 256, 0, stream>>>(x, wqkv, wproj, bqkv, bproj, mask,
                                     Xb, WqkvT, WprojT, bqkvF, bprojF, maskF);

    // QKV projection -> Q(,K)(,V^T with coalesced transpose epilogue)
    k_gemm<0><<<dim3(C3_/128, BT_/128), 256, 0, stream>>>(
        Xb, WqkvT, bqkvF, Qs, Ks, Vts, BT_, C3_, C_);
    // flash attention (round-8 structure: QBLK=128, 4 waves)
    k_attn<<<B_*H_*(T_/128), 256, 0, stream>>>(Qs, Ks, Vts, maskF, AO);
    // output projection -> f32 d_out
    k_gemm<1><<<dim3(C_/128, BT_/128), 256, 0, stream>>>(
        AO, WprojT, bprojF, d_out, nullptr, nullptr, BT_, C_, C_);
}

// Round 12
// 161.666 us; speedup vs baseline: 1.9357x; 1.0121x over previous
//
#include <hip/hip_runtime.h>
#include <stdint.h>

#define B_ 4
#define T_ 2048
#define C_ 768
#define H_ 12
#define D_ 64
#define BT_ (B_*T_)
#define C3_ (3*C_)
#define FMIN_ (-3.402823466e38f)
// 0.125 * log2(e): Q prescale so QK^T scores are in log2 units
#define QSCALE_ (0.18033688f)

typedef __attribute__((ext_vector_type(8))) short short8;
typedef __attribute__((ext_vector_type(4))) short s16x4;
typedef __attribute__((ext_vector_type(4))) float f32x4;

// async global->LDS DMA, 16B per lane; LDS dest = wave-uniform base + lane*16
#define GLDS16(g, l) __builtin_amdgcn_global_load_lds( \
    (const __attribute__((address_space(1))) void*)(g), \
    (__attribute__((address_space(3))) void*)(l), 16, 0, 0)

__device__ __forceinline__ float bf2f(unsigned short u) {
    union { unsigned int i; float f; } v; v.i = ((unsigned int)u) << 16; return v.f;
}
__device__ __forceinline__ unsigned short f2bf(float f) {
    union { float ff; unsigned int i; } v; v.ff = f;
    unsigned int r = v.i + 0x7fffu + ((v.i >> 16) & 1u);
    return (unsigned short)(r >> 16);
}
// packed f32x2 -> bf16x2 (RNE), single HW instr
__device__ __forceinline__ unsigned int cvtpk(float lo, float hi) {
    unsigned int r;
    asm("v_cvt_pk_bf16_f32 %0, %1, %2" : "=v"(r) : "v"(lo), "v"(hi));
    return r;
}
__device__ __forceinline__ float ldf(const void* p, size_t i, int isbf) {
    return isbf ? bf2f(((const unsigned short*)p)[i]) : ((const float*)p)[i];
}

// ---------------- wave-level self-detection ----------------
__device__ __forceinline__ int detect_bf16(const void* p) {
    unsigned short u = ((const unsigned short*)p)[2 * (threadIdx.x & 63)];
    int e = (u >> 7) & 0xff;
    unsigned long long m = __ballot(e >= 100 && e <= 140);
    return __popcll(m) >= 32;
}
// mask mode: 1=int32 (all dwords 0/1), 2=f32 (all 0.0/1.0), 0=uint8/bool
__device__ __forceinline__ int detect_mask(const void* p) {
    unsigned int d = ((const unsigned int*)p)[threadIdx.x & 63];
    unsigned long long bi = __ballot(d <= 1u);
    unsigned long long bf = __ballot(d == 0u || d == 0x3f800000u);
    if (__popcll(bi) == 64) return 1;
    if (__popcll(bf) == 64) return 2;
    return 0;
}

// ---------------- merged prep: x-canon + both weight transposes + biases + mask ----
__global__ void k_prep(const void* x, const void* wqkv, const void* wproj,
                       const void* bqkv, const void* bproj, const void* mask,
                       unsigned short* Xb, unsigned short* WqkvT, unsigned short* WprojT,
                       float* bqkvF, float* bprojF, float* maskF) {
    __shared__ float tile[32][33];
    int id = blockIdx.x;
    if (id < 3072) {
        int i = id * 256 + threadIdx.x;     // short8 index, exact coverage
        if (detect_bf16(x)) {
            ((int4*)Xb)[i] = ((const int4*)x)[i];
        } else {
            const float4* xf = (const float4*)x;
            float4 a = xf[2*i], b = xf[2*i+1];
            short8 o;
            o[0]=(short)f2bf(a.x); o[1]=(short)f2bf(a.y); o[2]=(short)f2bf(a.z); o[3]=(short)f2bf(a.w);
            o[4]=(short)f2bf(b.x); o[5]=(short)f2bf(b.y); o[6]=(short)f2bf(b.z); o[7]=(short)f2bf(b.w);
            *(short8*)&Xb[8*i] = o;
        }
    } else if (id < 5376) {
        id -= 3072;
        const void* src; unsigned short* dst; int K = C_, N, bx, by;
        if (id < 1728) { src = wqkv; dst = WqkvT; N = C3_; bx = id % 72; by = id / 72; }
        else { id -= 1728; src = wproj; dst = WprojT; N = C_; bx = id % 24; by = id / 24; }
        int mode = detect_bf16(src);
        int n0 = bx * 32, k0 = by * 32;
        int tx = threadIdx.x & 31, ty = threadIdx.x >> 5;
        for (int r = ty; r < 32; r += 8) {
            size_t idx = (size_t)(k0 + r) * N + (n0 + tx);
            tile[r][tx] = mode ? bf2f(((const unsigned short*)src)[idx])
                               : ((const float*)src)[idx];
        }
        __syncthreads();
        for (int r = ty; r < 32; r += 8)
            dst[(size_t)(n0 + r) * K + k0 + tx] = f2bf(tile[tx][r]);
    } else {
        int i = (id - 5376) * 256 + threadIdx.x;
        if (i < C3_) bqkvF[i] = ldf(bqkv, i, detect_bf16(bqkv));
        if (i < C_)  bprojF[i] = ldf(bproj, i, detect_bf16(bproj));
        if (i < BT_) {
            int mm = detect_mask(mask);
            int mv;
            if (mm == 1)      mv = ((const int*)mask)[i] != 0;
            else if (mm == 2) mv = ((const float*)mask)[i] != 0.0f;
            else              mv = ((const unsigned char*)mask)[i] != 0;
            maskF[i] = mv ? FMIN_ : 0.0f;
        }
    }
}

// ---------------- bf16 MFMA GEMM: C = A[M][K] * Bt[N][K]^T + bias ----------------
// (round-10 proven form: GLDS staging + both-sides XOR swizzle; V^T LDS-transpose)
// + bijective XCD swizzle on the flattened block id (total blocks % 8 == 0):
//   fid = by*gx + bx ; swz = (fid&7)*(total/8) + (fid>>3) -> contiguous per-XCD
//   row-panel chunks => A-panels L2-resident per XCD.
template<int EPI>
__global__ __launch_bounds__(256) void k_gemm(
        const unsigned short* __restrict__ A, const unsigned short* __restrict__ Bt,
        const float* __restrict__ bias,
        void* __restrict__ out0, unsigned short* __restrict__ out1,
        unsigned short* __restrict__ out2,
        int M, int N, int K) {
    __shared__ __align__(16) unsigned short smem[2*128*64];   // la | lb ; tr alias
    unsigned short* la = smem;
    unsigned short* lb = smem + 128*64;
    const int tid = threadIdx.x;
    const int w = tid >> 6, lane = tid & 63, lr = lane & 15, lg = lane >> 4;
    const int wm = (w >> 1) * 64, wn = (w & 1) * 64;
    // bijective XCD swizzle of the flattened block id
    const int gx = gridDim.x;
    const int total = gx * gridDim.y;
    const int fid = blockIdx.y * gx + blockIdx.x;
    const int swz = (fid & 7) * (total >> 3) + (fid >> 3);
    const int bx = swz % gx, by = swz / gx;
    const int n0 = bx * 128, m0 = by * 128;
    const int rin = lane >> 3;
    const int gslot = (lane & 7) ^ rin;     // pre-swizzled global 16B-slot
    f32x4 acc[4][4] = {};
    for (int k0 = 0; k0 < K; k0 += 64) {
#pragma unroll
        for (int c = 0; c < 4; ++c) {
            const int chunk = w * 4 + c;
            const int row = chunk * 8 + rin;
            GLDS16(&A[(size_t)(m0+row)*K + k0 + gslot*8], &la[chunk*512]);
            GLDS16(&Bt[(size_t)(n0+row)*K + k0 + gslot*8], &lb[chunk*512]);
        }
        __syncthreads();   // implicit vmcnt(0) drains the DMA
#pragma unroll
        for (int ks = 0; ks < 64; ks += 32) {
            short8 af[4], bfr[4];
            const int rs = (lg + (ks >> 3)) ^ (lr & 7);   // swizzled read slot
#pragma unroll
            for (int i = 0; i < 4; ++i)
                af[i] = *(const short8*)&la[(wm + i*16 + lr)*64 + rs*8];
#pragma unroll
            for (int j = 0; j < 4; ++j)
                bfr[j] = *(const short8*)&lb[(wn + j*16 + lr)*64 + rs*8];
#pragma unroll
            for (int i = 0; i < 4; ++i)
#pragma unroll
                for (int j = 0; j < 4; ++j)
                    acc[i][j] = __builtin_amdgcn_mfma_f32_16x16x32_bf16(af[i], bfr[j], acc[i][j], 0, 0, 0);
        }
        __syncthreads();   // all reads done before next-tile DMA (also frees smem)
    }
    if (EPI == 1) {
#pragma unroll
        for (int i = 0; i < 4; ++i)
#pragma unroll
            for (int j = 0; j < 4; ++j)
#pragma unroll
                for (int r = 0; r < 4; ++r) {
                    int row = m0 + wm + i*16 + lg*4 + r;
                    int col = n0 + wn + j*16 + lr;
                    ((float*)out0)[(size_t)row * N + col] = acc[i][j][r] + bias[col];
                }
        return;
    }
    // EPI 0: segment is block-uniform (n0 multiple of 128; boundaries 768/1536)
    const int seg0 = n0 / C_;
    if (seg0 < 2) {
#pragma unroll
        for (int i = 0; i < 4; ++i)
#pragma unroll
            for (int j = 0; j < 4; ++j)
#pragma unroll
                for (int r = 0; r < 4; ++r) {
                    int row = m0 + wm + i*16 + lg*4 + r;
                    int col = n0 + wn + j*16 + lr;
                    float v = acc[i][j][r] + bias[col];
                    int c = col - seg0 * C_;
                    int h = c >> 6, d = c & 63;
                    int b = row >> 11, t = row & (T_ - 1);
                    size_t idx = (((size_t)b*H_ + h)*T_ + t)*D_ + d;
                    if (seg0 == 0) ((unsigned short*)out0)[idx] = f2bf(v * QSCALE_);
                    else           out1[idx] = f2bf(v);
                }
    } else {
        // V block: transpose through LDS (reuse smem), store 16B t-contiguous runs.
        unsigned short* tr = smem;           // [64 cols][136 rows] bf16
        const int bidx = m0 >> 11;
        const int tbase = m0 & (T_ - 1);
#pragma unroll
        for (int p = 0; p < 2; ++p) {
            if ((w & 1) == p) {
#pragma unroll
                for (int i = 0; i < 4; ++i)
#pragma unroll
                    for (int j = 0; j < 4; ++j)
#pragma unroll
                        for (int r = 0; r < 4; ++r) {
                            int col = n0 + wn + j*16 + lr;
                            float v = acc[i][j][r] + bias[col];
                            tr[(j*16 + lr)*136 + wm + i*16 + lg*4 + r] = f2bf(v);
                        }
            }
            __syncthreads();
            {
                int lc = tid >> 2, k4 = tid & 3;
                int c = n0 + p*64 + lc - 2*C_;
                int h = c >> 6, d = c & 63;
                unsigned short* dst = out2 + (((size_t)bidx*H_ + h)*D_ + d)*T_ + tbase;
#pragma unroll
                for (int s = 0; s < 4; ++s) {
                    int t0 = (k4 + s*4) * 8;
                    *(short8*)&dst[t0] = *(const short8*)&tr[lc*136 + t0];
                }
            }
            __syncthreads();
        }
    }
}

// ---------------- flash attention, swapped QK^T, log2-domain softmax ----------------
// (round-8/10 proven structure, byte-identical: QBLK=128, 4 waves, LDS-staged K/V,
// two barriers/tile)
__global__ __launch_bounds__(256) void k_attn(
        const unsigned short* __restrict__ Q, const unsigned short* __restrict__ Kt,
        const unsigned short* __restrict__ Vt, const float* __restrict__ maskF,
        unsigned short* __restrict__ AO) {
    __shared__ __align__(16) unsigned short lk[64*72];
    __shared__ __align__(16) unsigned short lv[64*72];
    __shared__ __align__(16) float lmb[64];
    const int tid = threadIdx.x;
    const int w = tid >> 6, lane = tid & 63, lr = lane & 15, lg = lane >> 4;
    // bijective XCD swizzle: 768 blocks = 8 XCD x 96; 16 consecutive share one bh's K/V
    const int per = gridDim.x >> 3;
    const int swz = (blockIdx.x & 7) * per + (blockIdx.x >> 3);
    const int bh = swz >> 4, qt = swz & 15;
    const int b = bh / H_, h = bh - b * H_;
    const int qbase = qt * 128 + w * 32;
    const unsigned short* Qb = Q  + (size_t)bh * T_ * D_;
    const unsigned short* Kb = Kt + (size_t)bh * T_ * D_;
    const unsigned short* Vb = Vt + (size_t)bh * D_ * T_;

    // Q as B-operand: lane holds col q=qc*16+lr, k-elems d = dh*32+lg*8..+7
    short8 qf[2][2];
#pragma unroll
    for (int qc = 0; qc < 2; ++qc)
#pragma unroll
        for (int dh = 0; dh < 2; ++dh)
            qf[qc][dh] = *(const short8*)&Qb[(size_t)(qbase + qc*16 + lr) * D_ + dh*32 + lg*8];

    f32x4 ot[4][2] = {};           // O^T[dblk][qc]
    float m[2] = {-INFINITY, -INFINITY}, l[2] = {0.0f, 0.0f};

    for (int kt = 0; kt < T_; kt += 64) {
#pragma unroll
        for (int c = 0; c < 2; ++c) {
            int idx = tid + c * 256;
            int row = idx >> 3, c8 = (idx & 7) * 8;
            *(short8*)&lk[row*72 + c8] = *(const short8*)&Kb[(size_t)(kt + row)*D_ + c8];
            *(short8*)&lv[row*72 + c8] = *(const short8*)&Vb[(size_t)row * T_ + kt + c8];
        }
        if (tid < 64) lmb[tid] = maskF[b*T_ + kt + tid];
        __syncthreads();

        // C-init = mask bias per key (shared by both qc); mask add is free+exact
        f32x4 st[4][2];
#pragma unroll
        for (int kf = 0; kf < 4; ++kf) {
            f32x4 mi = *(const f32x4*)&lmb[kf*16 + lg*4];
            st[kf][0] = mi;
            st[kf][1] = mi;
        }
        // S^T = K Q^T + mask
#pragma unroll
        for (int dh = 0; dh < 2; ++dh) {
            short8 kfr[4];
#pragma unroll
            for (int kf = 0; kf < 4; ++kf)
                kfr[kf] = *(const short8*)&lk[(kf*16 + lr)*72 + dh*32 + lg*8];
#pragma unroll
            for (int kf = 0; kf < 4; ++kf)
#pragma unroll
                for (int qc = 0; qc < 2; ++qc)
                    st[kf][qc] = __builtin_amdgcn_mfma_f32_16x16x32_bf16(kfr[kf], qf[qc][dh], st[kf][qc], 0, 0, 0);
        }
        // online softmax per qc (row = q = qc*16+lr; spread over 4 lanes lg)
#pragma unroll
        for (int qc = 0; qc < 2; ++qc) {
            float t0 = fmaxf(fmaxf(st[0][qc][0], st[0][qc][1]), st[0][qc][2]);
            float t1 = fmaxf(fmaxf(st[0][qc][3], st[1][qc][0]), st[1][qc][1]);
            float t2 = fmaxf(fmaxf(st[1][qc][2], st[1][qc][3]), st[2][qc][0]);
            float t3 = fmaxf(fmaxf(st[2][qc][1], st[2][qc][2]), st[2][qc][3]);
            float t4 = fmaxf(fmaxf(st[3][qc][0], st[3][qc][1]), st[3][qc][2]);
            float tm = fmaxf(fmaxf(t0, t1), fmaxf(fmaxf(t2, t3), fmaxf(t4, st[3][qc][3])));
            tm = fmaxf(tm, __shfl_xor(tm, 16));
            tm = fmaxf(tm, __shfl_xor(tm, 32));
            // defer-max: skip rescale while max growth <= 8 (p bounded by 2^8)
            if (!__all(tm - m[qc] <= 8.0f)) {
                float mn = fmaxf(m[qc], tm);
                float sc = __builtin_amdgcn_exp2f(m[qc] - mn);
                m[qc] = mn;
                l[qc] *= sc;
#pragma unroll
                for (int dblk = 0; dblk < 4; ++dblk) ot[dblk][qc] *= sc;
            }
            float mr = m[qc];
            float ps = 0.0f;
#pragma unroll
            for (int kf = 0; kf < 4; ++kf)
#pragma unroll
                for (int r = 0; r < 4; ++r) {
                    float p = __builtin_amdgcn_exp2f(st[kf][qc][r] - mr);
                    st[kf][qc][r] = p;
                    ps += p;
                }
            l[qc] += ps;
        }
        // pack P in-lane into relabeled B-fragments: pb[qc][ks]
        union PU { unsigned int u[4]; short8 s; };
        PU pb[2][2];
#pragma unroll
        for (int qc = 0; qc < 2; ++qc)
#pragma unroll
            for (int ks = 0; ks < 2; ++ks) {
                pb[qc][ks].u[0] = cvtpk(st[2*ks][qc][0],   st[2*ks][qc][1]);
                pb[qc][ks].u[1] = cvtpk(st[2*ks][qc][2],   st[2*ks][qc][3]);
                pb[qc][ks].u[2] = cvtpk(st[2*ks+1][qc][0], st[2*ks+1][qc][1]);
                pb[qc][ks].u[3] = cvtpk(st[2*ks+1][qc][2], st[2*ks+1][qc][3]);
            }
        // O^T += V^T P^T with matching slot relabel: A-slot (ks,j):
        //   j=0..3 -> key 32ks+lg*4+j ; j=4..7 -> key 32ks+16+lg*4+(j-4)
#pragma unroll
        for (int ks = 0; ks < 2; ++ks)
#pragma unroll
            for (int dblk = 0; dblk < 4; ++dblk) {
                const int rb = (dblk*16 + lr)*72 + 32*ks + lg*4;
                s16x4 lo = *(const s16x4*)&lv[rb];
                s16x4 hi = *(const s16x4*)&lv[rb + 16];
                short8 va;
                va[0]=lo[0]; va[1]=lo[1]; va[2]=lo[2]; va[3]=lo[3];
                va[4]=hi[0]; va[5]=hi[1]; va[6]=hi[2]; va[7]=hi[3];
#pragma unroll
                for (int qc = 0; qc < 2; ++qc)
                    ot[dblk][qc] = __builtin_amdgcn_mfma_f32_16x16x32_bf16(va, pb[qc][ks].s, ot[dblk][qc], 0, 0, 0);
            }
        __syncthreads();
    }
    // epilogue: reduce l across lg, normalize, store O^T -> AO rows
#pragma unroll
    for (int qc = 0; qc < 2; ++qc) {
        float ls = l[qc];
        ls += __shfl_xor(ls, 16);
        ls += __shfl_xor(ls, 32);
        float inv = 1.0f / ls;
        size_t row = (size_t)b*T_ + qbase + qc*16 + lr;
#pragma unroll
        for (int dblk = 0; dblk < 4; ++dblk) {
            unsigned int w0 = cvtpk(ot[dblk][qc][0]*inv, ot[dblk][qc][1]*inv);
            unsigned int w1 = cvtpk(ot[dblk][qc][2]*inv, ot[dblk][qc][3]*inv);
            uint2 pkd; pkd.x = w0; pkd.y = w1;
            *(uint2*)&AO[row * C_ + h*64 + dblk*16 + lg*4] = pkd;
        }
    }
}

extern "C" void kernel_launch(void* const* d_in, const int* in_sizes, int n_in,
                              void* d_out, int out_size, void* d_ws, size_t ws_size,
                              hipStream_t stream) {
    const void* x     = d_in[0];
    const void* mask  = d_in[1];
    const void* wqkv  = d_in[2];
    const void* bqkv  = d_in[3];
    const void* wproj = d_in[4];
    const void* bproj = d_in[5];

    char* ws = (char*)d_ws;
    size_t off = 0;
    auto alloc = [&](size_t bytes) -> void* {
        void* p = ws + off;
        off = (off + bytes + 255) & ~(size_t)255;
        return p;
    };
    unsigned short* Xb    = (unsigned short*)alloc((size_t)BT_ * C_ * 2);
    unsigned short* WqkvT = (unsigned short*)alloc((size_t)C3_ * C_ * 2);
    unsigned short* WprojT= (unsigned short*)alloc((size_t)C_ * C_ * 2);
    float* bqkvF          = (float*)alloc((size_t)C3_ * 4);
    float* bprojF         = (float*)alloc((size_t)C_ * 4);
    float* maskF          = (float*)alloc((size_t)BT_ * 4);
    unsigned short* Qs    = (unsigned short*)alloc((size_t)B_*H_*T_*D_ * 2);
    unsigned short* Ks    = (unsigned short*)alloc((size_t)B_*H_*T_*D_ * 2);
    unsigned short* Vts   = (unsigned short*)alloc((size_t)B_*H_*T_*D_ * 2);
    unsigned short* AO    = (unsigned short*)alloc((size_t)BT_ * C_ * 2);

    // merged prep: x-canon + weight transposes + biases + mask
    k_prep<<<5408, 256, 0, stream>>>(x, wqkv, wproj, bqkv, bproj, mask,
                                     Xb, WqkvT, WprojT, bqkvF, bprojF, maskF);

    // QKV projection -> Q(,K)(,V^T with coalesced transpose epilogue)
    k_gemm<0><<<dim3(C3_/128, BT_/128), 256, 0, stream>>>(
        Xb, WqkvT, bqkvF, Qs, Ks, Vts, BT_, C3_, C_);
    // flash attention (round-8/10 structure: QBLK=128, 4 waves)
    k_attn<<<B_*H_*(T_/128), 256, 0, stream>>>(Qs, Ks, Vts, maskF, AO);
    // output projection -> f32 d_out
    k_gemm<1><<<dim3(C_/128, BT_/128), 256, 0, stream>>>(
        AO, WprojT, bprojF, d_out, nullptr, nullptr, BT_, C_, C_);
}